// Round 6
// baseline (229.574 us; speedup 1.0000x reference)
//
#include <hip/hip_runtime.h>

// R13: two changes. (a) Revert GEMM to the measured-better single-buffer
// 2-barrier schedule (dbuf: 74us vs single 54.6 -- DMA LDS-writes contended
// with the ds_read-heavy compute phase; latency was already TLP-hidden).
// (b) DELETE cast_all: GEMMs reg-stage operands with inline f32->bf16
// (global f32x4 loads -> cvt_pk -> ds_write_b128, same XOR-swizzled LDS
// layout; next step's loads issued under current MFMAs = T14). 4 launches
// -> 3. This is also a deliberate test of the additive-vs-fixed-overhead
// model: totals have been pinned at ~227 for six rounds while profiled
// components swung +-25us. If total doesn't move now, the bottleneck is
// launch/serialization overhead, not kernel time.
#define DIM 512
#define NQ 2048
#define MA 2048
#define MS 256
#define QSCALE 0.06375864651f  // 512^-0.5 * log2(e)

typedef __attribute__((ext_vector_type(8))) short bf16x8;
typedef __attribute__((ext_vector_type(4))) float f32x4;
typedef __attribute__((ext_vector_type(16))) float f32x16;

__device__ __forceinline__ ushort f2b(float f) {
    uint u = __float_as_uint(f);
    u = (u + 0x7fffu + ((u >> 16) & 1u)) >> 16;
    return (ushort)u;
}

__device__ __forceinline__ uint pk2bf(float a, float b) {
#if __has_builtin(__builtin_amdgcn_cvt_pk_bf16_f32)
    typedef __attribute__((ext_vector_type(2))) __bf16 bf2;
    bf2 r = __builtin_amdgcn_cvt_pk_bf16_f32(a, b);
    uint u;
    __builtin_memcpy(&u, &r, 4);
    return u;
#else
    return ((__float_as_uint(a) + 0x8000u) >> 16) |
           ((__float_as_uint(b) + 0x8000u) & 0xffff0000u);
#endif
}

__device__ __forceinline__ float fexp2(float x) {
#if __has_builtin(__builtin_amdgcn_exp2f)
    return __builtin_amdgcn_exp2f(x);
#else
    return exp2f(x);
#endif
}

// ---- fused GEMM: C = A @ B^T + bias, 128x128 tile, BK=32, single-buffer ----
// AF32/BF32: operand element type (1 = f32 in global, cast during staging).
// Reg-staged: global loads -> regs (issued during previous step's MFMAs),
// cvt -> ds_write_b128 into the same XOR-swizzled [128][32] bf16 layout.
struct GD {
    const void* A; const void* B; const float* bias; void* out;
    long sB, sO;
    int N, bx, by, blk0, biasrow, scaleq, outf32, permc;
};

template <int AF32, int BF32>
__global__ __launch_bounds__(256) void gemm_t(GD d0, GD d1, GD d2, GD d3, GD d4) {
    __shared__ ushort At[128 * 32];
    __shared__ ushort Bt[128 * 32];
    GD d = d0;
    int bid = blockIdx.x;
    if (bid >= d1.blk0) d = d1;
    if (bid >= d2.blk0) d = d2;
    if (bid >= d3.blk0) d = d3;
    if (bid >= d4.blk0) d = d4;
    int local = bid - d.blk0;
    int x = local % d.bx;
    int rem = local / d.bx;
    int y = rem % d.by;
    int z = rem / d.by;

    int t = threadIdx.x;
    int wv = t >> 6, ln = t & 63, l = ln & 15, g = ln >> 4;
    int wrow = wv & 1, wcol = wv >> 1;
    int row0 = x * 128, col0 = y * 128;
    int srow = t >> 2;
    int slot = (t & 3) * 8;
    int sko = ((t ^ srow) & 3) * 8;        // XOR-swizzled global k-chunk
    int kc8 = ((g ^ (l & 3)) & 3) * 8;     // reader un-swizzle
    int l4 = (l >> 2) & 3;
    int lp = d.permc ? (l4 == 1 ? l + 4 : (l4 == 2 ? l - 4 : l)) : l;
    int N = d.N;
    int so0 = srow * 32 + slot;
    int so1 = (srow + 64) * 32 + slot;

    // staging registers (reused every step)
    float4 fa[4], fb[4];
    bf16x8 ha[2], hb[2];

    auto issue = [&](int k0) {
        if (AF32) {
            const float* A0 = (const float*)d.A + (size_t)(row0 + srow) * 512 + k0 + sko;
            const float* A1 = (const float*)d.A + (size_t)(row0 + srow + 64) * 512 + k0 + sko;
            fa[0] = *(const float4*)A0; fa[1] = *(const float4*)(A0 + 4);
            fa[2] = *(const float4*)A1; fa[3] = *(const float4*)(A1 + 4);
        } else {
            const ushort* A0 = (const ushort*)d.A + (size_t)(row0 + srow) * 512 + k0 + sko;
            const ushort* A1 = (const ushort*)d.A + (size_t)(row0 + srow + 64) * 512 + k0 + sko;
            ha[0] = *(const bf16x8*)A0;
            ha[1] = *(const bf16x8*)A1;
        }
        if (BF32) {
            const float* Bb = (const float*)d.B + (size_t)z * d.sB;
            const float* B0 = Bb + (size_t)(col0 + srow) * 512 + k0 + sko;
            const float* B1 = Bb + (size_t)(col0 + srow + 64) * 512 + k0 + sko;
            fb[0] = *(const float4*)B0; fb[1] = *(const float4*)(B0 + 4);
            fb[2] = *(const float4*)B1; fb[3] = *(const float4*)(B1 + 4);
        } else {
            const ushort* Bb = (const ushort*)d.B + (size_t)z * d.sB;
            const ushort* B0 = Bb + (size_t)(col0 + srow) * 512 + k0 + sko;
            const ushort* B1 = Bb + (size_t)(col0 + srow + 64) * 512 + k0 + sko;
            hb[0] = *(const bf16x8*)B0;
            hb[1] = *(const bf16x8*)B1;
        }
    };

    auto wstage = [&]() {
        if (AF32) {
            union { bf16x8 v; uint u[4]; } w0, w1;
            w0.u[0] = pk2bf(fa[0].x, fa[0].y); w0.u[1] = pk2bf(fa[0].z, fa[0].w);
            w0.u[2] = pk2bf(fa[1].x, fa[1].y); w0.u[3] = pk2bf(fa[1].z, fa[1].w);
            w1.u[0] = pk2bf(fa[2].x, fa[2].y); w1.u[1] = pk2bf(fa[2].z, fa[2].w);
            w1.u[2] = pk2bf(fa[3].x, fa[3].y); w1.u[3] = pk2bf(fa[3].z, fa[3].w);
            *(bf16x8*)(At + so0) = w0.v;
            *(bf16x8*)(At + so1) = w1.v;
        } else {
            *(bf16x8*)(At + so0) = ha[0];
            *(bf16x8*)(At + so1) = ha[1];
        }
        if (BF32) {
            union { bf16x8 v; uint u[4]; } w0, w1;
            w0.u[0] = pk2bf(fb[0].x, fb[0].y); w0.u[1] = pk2bf(fb[0].z, fb[0].w);
            w0.u[2] = pk2bf(fb[1].x, fb[1].y); w0.u[3] = pk2bf(fb[1].z, fb[1].w);
            w1.u[0] = pk2bf(fb[2].x, fb[2].y); w1.u[1] = pk2bf(fb[2].z, fb[2].w);
            w1.u[2] = pk2bf(fb[3].x, fb[3].y); w1.u[3] = pk2bf(fb[3].z, fb[3].w);
            *(bf16x8*)(Bt + so0) = w0.v;
            *(bf16x8*)(Bt + so1) = w1.v;
        } else {
            *(bf16x8*)(Bt + so0) = hb[0];
            *(bf16x8*)(Bt + so1) = hb[1];
        }
    };

    f32x4 acc[4][4];
#pragma unroll
    for (int i = 0; i < 4; i++)
#pragma unroll
        for (int j = 0; j < 4; j++) acc[i][j] = (f32x4){0, 0, 0, 0};

    issue(0);  // prologue: loads for step 0 in flight

#pragma unroll 1
    for (int k0 = 0; k0 < 512; k0 += 32) {
        __syncthreads();           // previous step's LDS reads complete
        wstage();                  // vmcnt-wait (auto) + cvt + ds_write
        __syncthreads();           // staged tile visible
        if (k0 + 32 < 512) issue(k0 + 32);  // next loads fly under MFMAs
        bf16x8 ar[4], br[4];
#pragma unroll
        for (int i = 0; i < 4; i++)
            ar[i] = *(const bf16x8*)(At + (wrow * 64 + i * 16 + l) * 32 + kc8);
#pragma unroll
        for (int j = 0; j < 4; j++)
            br[j] = *(const bf16x8*)(Bt + (wcol * 64 + j * 16 + l) * 32 + kc8);
#pragma unroll
        for (int i = 0; i < 4; i++)
#pragma unroll
            for (int j = 0; j < 4; j++)
                acc[i][j] = __builtin_amdgcn_mfma_f32_16x16x32_bf16(ar[i], br[j], acc[i][j], 0, 0, 0);
    }
#pragma unroll
    for (int i = 0; i < 4; i++) {
#pragma unroll
        for (int j = 0; j < 4; j++) {
            int row = row0 + wrow * 64 + i * 16 + g * 4;
            int col = col0 + wcol * 64 + j * 16 + lp;
#pragma unroll
            for (int r = 0; r < 4; r++) {
                float bv = d.biasrow ? d.bias[row + r] : d.bias[col];
                float o = acc[i][j][r] + bv;
                if (d.scaleq) o *= QSCALE;
                if (d.outf32)
                    ((float*)d.out + (size_t)z * d.sO)[(size_t)(row + r) * N + col] = o;
                else
                    ((ushort*)d.out + (size_t)z * d.sO)[(size_t)(row + r) * N + col] = f2b(o);
            }
        }
    }
}

// ---- attention: 32x32x16, K/V dbuf LDS (1 barrier/tile), P in registers ----
// (R9 version, measured 60.6us, unchanged.)
__device__ __forceinline__ void attn_ctx32(const ushort* __restrict__ kg,
                                           const ushort* __restrict__ vg,
                                           int M, int nt, const bf16x8 (&aq)[4],
                                           ushort* __restrict__ Kl,
                                           ushort* __restrict__ Vl,
                                           f32x16 (&o)[2], float& li,
                                           int l5, int hi, int sr, int sc, int vbase) {
    bf16x8 k0 = *(const bf16x8*)kg;
    bf16x8 k1 = *(const bf16x8*)(kg + (size_t)32 * DIM);
    bf16x8 v0 = *(const bf16x8*)vg;
    bf16x8 v1 = *(const bf16x8*)(vg + (size_t)32 * M);
    __syncthreads();
    {   // tile 0 -> buf 0
        *(bf16x8*)(Kl + sr * 72 + sc) = k0;
        *(bf16x8*)(Kl + (sr + 32) * 72 + sc) = k1;
        union { bf16x8 v; uint2 h[2]; } cv;
        cv.v = v0;
        *(uint2*)(Vl + sr * 72 + vbase) = cv.h[0];
        *(uint2*)(Vl + sr * 72 + vbase + 8) = cv.h[1];
        cv.v = v1;
        *(uint2*)(Vl + (sr + 32) * 72 + vbase) = cv.h[0];
        *(uint2*)(Vl + (sr + 32) * 72 + vbase + 8) = cv.h[1];
    }
    if (nt > 1) {
        k0 = *(const bf16x8*)(kg + (size_t)64 * DIM);
        k1 = *(const bf16x8*)(kg + (size_t)96 * DIM);
        v0 = *(const bf16x8*)(vg + 64);
        v1 = *(const bf16x8*)(vg + (size_t)32 * M + 64);
    }
    for (int i = 0; i < nt; i++) {
        __syncthreads();
        if (i + 1 < nt) {
            ushort* Kb = Kl + ((i + 1) & 1) * (64 * 72);
            ushort* Vb = Vl + ((i + 1) & 1) * (64 * 72);
            *(bf16x8*)(Kb + sr * 72 + sc) = k0;
            *(bf16x8*)(Kb + (sr + 32) * 72 + sc) = k1;
            union { bf16x8 v; uint2 h[2]; } cv;
            cv.v = v0;
            *(uint2*)(Vb + sr * 72 + vbase) = cv.h[0];
            *(uint2*)(Vb + sr * 72 + vbase + 8) = cv.h[1];
            cv.v = v1;
            *(uint2*)(Vb + (sr + 32) * 72 + vbase) = cv.h[0];
            *(uint2*)(Vb + (sr + 32) * 72 + vbase + 8) = cv.h[1];
        }
        if (i + 2 < nt) {
            size_t off = (size_t)(i + 2) * 64;
            k0 = *(const bf16x8*)(kg + off * DIM);
            k1 = *(const bf16x8*)(kg + (off + 32) * DIM);
            v0 = *(const bf16x8*)(vg + off);
            v1 = *(const bf16x8*)(vg + (size_t)32 * M + off);
        }
        const ushort* Kc = Kl + (i & 1) * (64 * 72);
        const ushort* Vc = Vl + (i & 1) * (64 * 72);
        uint2 pq[2][4];
#pragma unroll
        for (int c = 0; c < 2; c++) {
            bf16x8 kf[4];
#pragma unroll
            for (int kd = 0; kd < 4; kd++)
                kf[kd] = *(const bf16x8*)(Kc + (32 * c + l5) * 72 + kd * 16 + hi * 8);
            f32x16 s;
#pragma unroll
            for (int ii = 0; ii < 16; ii++) s[ii] = 0.f;
#pragma unroll
            for (int kd = 0; kd < 4; kd++)
                s = __builtin_amdgcn_mfma_f32_32x32x16_bf16(kf[kd], aq[kd], s, 0, 0, 0);
#pragma unroll
            for (int m = 0; m < 4; m++) {
                float p0 = fexp2(s[4 * m + 0]);
                float p1 = fexp2(s[4 * m + 1]);
                float p2 = fexp2(s[4 * m + 2]);
                float p3 = fexp2(s[4 * m + 3]);
                li += (p0 + p1) + (p2 + p3);
                pq[c][m].x = pk2bf(p0, p1);
                pq[c][m].y = pk2bf(p2, p3);
            }
        }
#pragma unroll
        for (int kc = 0; kc < 4; kc++) {
            int c = kc >> 1, m0 = 2 * (kc & 1);
            union { bf16x8 v; uint u[4]; } w;
            w.u[0] = pq[c][m0].x;     w.u[1] = pq[c][m0].y;
            w.u[2] = pq[c][m0 + 1].x; w.u[3] = pq[c][m0 + 1].y;
#pragma unroll
            for (int dn = 0; dn < 2; dn++) {
                bf16x8 vf = *(const bf16x8*)(Vc + (32 * dn + l5) * 72 + kc * 16 + hi * 8);
                o[dn] = __builtin_amdgcn_mfma_f32_32x32x16_bf16(w.v, vf, o[dn], 0, 0, 0);
            }
        }
    }
}

__global__ __launch_bounds__(512, 2) void attn_kernel(const ushort* __restrict__ q,
                                                      const ushort* __restrict__ Ka,
                                                      const ushort* __restrict__ VTa,
                                                      const ushort* __restrict__ Ks,
                                                      const ushort* __restrict__ VTs,
                                                      ushort* __restrict__ y) {
    __shared__ ushort smem[2 * 18432];  // [grp][Kl 9216 | Vl 9216]
    int t = threadIdx.x;
    int grp = t >> 8;
    int tg = t & 255;
    int wg = tg >> 6;
    int ln = t & 63, l5 = ln & 31, hi = ln >> 5;
    ushort* Kl = smem + grp * 18432;
    ushort* Vl = Kl + 9216;
    float* osc = (float*)(smem + 18432);  // overlay of group 1's region
    int h = blockIdx.y, bi = blockIdx.z;
    int q0 = blockIdx.x * 128 + wg * 32;
    bf16x8 aq[4];
    const ushort* qp = q + (size_t)(bi * NQ + q0 + l5) * DIM + h * 64 + hi * 8;
#pragma unroll
    for (int kd = 0; kd < 4; kd++) aq[kd] = *(const bf16x8*)(qp + kd * 16);
    int sr = tg >> 3, sc = (tg & 7) * 8;
    int vbase = (sc >> 4) * 16 + ((sc >> 3) & 1) * 4;  // permuted V slot base

    f32x16 o[2];
#pragma unroll
    for (int dn = 0; dn < 2; dn++)
#pragma unroll
        for (int i = 0; i < 16; i++) o[dn][i] = 0.f;
    float li = 0.f;

    // audio (long) first: group grp handles ctx [grp*1024, grp*1024+1024)
    attn_ctx32(Ka + (size_t)bi * MA * DIM + (size_t)(grp * 1024 + sr) * DIM + h * 64 + sc,
               VTa + (size_t)bi * DIM * MA + (size_t)(h * 64 + sr) * MA + grp * 1024 + sc,
               MA, 16, aq, Kl, Vl, o, li, l5, hi, sr, sc, vbase);
    li += __shfl_xor(li, 32);
    __syncthreads();  // all LDS reads of this phase done
    if (grp) {
        float* p = osc + (wg * 64 + ln) * 34;
#pragma unroll
        for (int dn = 0; dn < 2; dn++)
#pragma unroll
            for (int k = 0; k < 8; k++)
                *(float2*)(p + dn * 16 + 2 * k) = (float2){o[dn][2 * k], o[dn][2 * k + 1]};
        p[32] = li;
    }
    __syncthreads();  // partials visible
    float yv[2][16];
    if (!grp) {
        const float* p = osc + (wg * 64 + ln) * 34;
#pragma unroll
        for (int dn = 0; dn < 2; dn++)
#pragma unroll
            for (int k = 0; k < 16; k++) o[dn][k] += p[dn * 16 + k];
        li += p[32];
        float inv[16];
#pragma unroll
        for (int rg = 0; rg < 16; rg++)
            inv[rg] = 1.f / __shfl(li, (rg & 3) + 8 * (rg >> 2) + 4 * hi);
#pragma unroll
        for (int dn = 0; dn < 2; dn++)
#pragma unroll
            for (int rg = 0; rg < 16; rg++) yv[dn][rg] = o[dn][rg] * inv[rg];
    }

#pragma unroll
    for (int dn = 0; dn < 2; dn++)
#pragma unroll
        for (int i = 0; i < 16; i++) o[dn][i] = 0.f;
    li = 0.f;
    // singer (short): group grp handles ctx [grp*128, grp*128+128)
    attn_ctx32(Ks + (size_t)bi * MS * DIM + (size_t)(grp * 128 + sr) * DIM + h * 64 + sc,
               VTs + (size_t)bi * DIM * MS + (size_t)(h * 64 + sr) * MS + grp * 128 + sc,
               MS, 2, aq, Kl, Vl, o, li, l5, hi, sr, sc, vbase);
    li += __shfl_xor(li, 32);
    __syncthreads();
    if (grp) {
        float* p = osc + (wg * 64 + ln) * 34;
#pragma unroll
        for (int dn = 0; dn < 2; dn++)
#pragma unroll
            for (int k = 0; k < 8; k++)
                *(float2*)(p + dn * 16 + 2 * k) = (float2){o[dn][2 * k], o[dn][2 * k + 1]};
        p[32] = li;
    }
    __syncthreads();
    if (!grp) {
        const float* p = osc + (wg * 64 + ln) * 34;
#pragma unroll
        for (int dn = 0; dn < 2; dn++)
#pragma unroll
            for (int k = 0; k < 16; k++) o[dn][k] += p[dn * 16 + k];
        li += p[32];
        float inv[16];
#pragma unroll
        for (int rg = 0; rg < 16; rg++)
            inv[rg] = 1.f / __shfl(li, (rg & 3) + 8 * (rg >> 2) + 4 * hi);
        // O: lane holds d = 32*dn + l5, q = (rg&3)+8*(rg>>2)+4*hi
#pragma unroll
        for (int dn = 0; dn < 2; dn++)
#pragma unroll
            for (int rg = 0; rg < 16; rg++) {
                int qr = (rg & 3) + 8 * (rg >> 2) + 4 * hi;
                float ov = yv[dn][rg] + o[dn][rg] * inv[rg];
                y[(size_t)(bi * NQ + q0 + qr) * DIM + h * 64 + 32 * dn + l5] = f2b(ov);
            }
    }
}

extern "C" void kernel_launch(void* const* d_in, const int* in_sizes, int n_in,
                              void* d_out, int out_size, void* d_ws, size_t ws_size,
                              hipStream_t stream) {
    const float* x   = (const float*)d_in[0];
    const float* ac  = (const float*)d_in[1];
    const float* scx = (const float*)d_in[2];
    const float* Wq  = (const float*)d_in[3];
    const float* bq  = (const float*)d_in[4];
    const float* Wka = (const float*)d_in[5];
    const float* bka = (const float*)d_in[6];
    const float* Wva = (const float*)d_in[7];
    const float* bva = (const float*)d_in[8];
    const float* Wks = (const float*)d_in[9];
    const float* bks = (const float*)d_in[10];
    const float* Wvs = (const float*)d_in[11];
    const float* bvs = (const float*)d_in[12];
    const float* Wp  = (const float*)d_in[13];
    const float* bp  = (const float*)d_in[14];

    ushort* qb  = (ushort*)d_ws;          // [8192][512] prescaled q (bf16)
    ushort* kab = qb + 4194304;           // [8192][512]
    ushort* vta = kab + 4194304;          // [4][512][2048] V^T
    ushort* ksb = vta + 4194304;          // [1024][512]
    ushort* vts = ksb + 524288;           // [4][512][256]  V^T
    ushort* yb  = vts + 524288;           // [8192][512] attn out

    // all f32 inputs consumed directly; conversion happens in GEMM staging
    GD gq   = {x,   Wq,  bq,  qb,  0, 0,                    512,  64, 4,  0,   0, 1, 0, 0};
    GD gka  = {ac,  Wka, bka, kab, 0, 0,                    512,  64, 4,  256, 0, 0, 0, 0};
    GD gvta = {Wva, ac,  bva, vta, 2048L * 512, 512L * 2048, 2048, 4, 16, 512, 1, 0, 0, 0};
    GD gks  = {scx, Wks, bks, ksb, 0, 0,                    512,  8,  4,  768, 0, 0, 0, 0};
    GD gvts = {Wvs, scx, bvs, vts, 256L * 512, 512L * 256,   256,  4,  2,  800, 1, 0, 0, 0};
    gemm_t<1, 1><<<832, 256, 0, stream>>>(gq, gka, gvta, gks, gvts);

    attn_kernel<<<dim3(16, 8, 4), 512, 0, stream>>>(qb, kab, vta, ksb, vts, yb);

    GD gpr = {yb, Wp, bp, d_out, 0, 0, 512, 64, 4, 0, 0, 0, 1, 0};
    GD gnv = {nullptr, nullptr, nullptr, nullptr, 0, 0, 0, 1, 1, 1 << 30, 0, 0, 0, 0};
    gemm_t<0, 1><<<256, 256, 0, stream>>>(gpr, gnv, gnv, gnv, gnv);
}